// Round 1
// baseline (619.526 us; speedup 1.0000x reference)
//
#include <hip/hip_runtime.h>

typedef short short8 __attribute__((ext_vector_type(8)));
typedef float f32x4 __attribute__((ext_vector_type(4)));

#define ROWS 65536     // B*C*S = 1024*64
#define NELT 16777216  // B*S*C*D per tensor

__device__ __forceinline__ float b2f(unsigned short u) {
    return __uint_as_float(((unsigned)u) << 16);
}
__device__ __forceinline__ unsigned short f2b(float f) {
    unsigned u = __float_as_uint(f);
    u += 0x7FFF + ((u >> 16) & 1);   // RTN-even
    return (unsigned short)(u >> 16);
}
// Markidis split: f ~= b2f(hi) + b2f(lo), residual ~2^-18 relative
__device__ __forceinline__ void split2(float f, unsigned short& hi, unsigned short& lo) {
    unsigned short h = f2b(f);
    hi = h;
    lo = f2b(f - b2f(h));
}
// row r of the (BC*S, D) flattened view -> flat offset into x (B,S,C,D)
__device__ __forceinline__ int xrow_off(int r) {
    int n = r >> 6, s = r & 63;      // n = b*128+c, s = token
    int b = n >> 7, c = n & 127;
    return (((b << 6) + s) * 128 + c) << 8;  // ((b*64+s)*128+c)*256
}
// XOR-swizzled LDS element offset, 64x256 bf16 tile, 8-elem chunks.
// (row&7) < 8 so the XOR only permutes the low-3 chunk bits.
__device__ __forceinline__ int sw256(int row, int k) {
    return row * 256 + ((((k >> 3) ^ (row & 7)) << 3) | (k & 7));
}
// linearized B-fragment offset (in shorts): [nt][kk][ct][lq][lm][hi8|lo8]
__device__ __forceinline__ int boff(int nt, int kk, int ct, int lq, int lm) {
    return ((((nt * 8 + kk) * 4 + ct) * 4 + lq) * 16 + lm) * 16;
}

// ---- weight pre-linearization into MFMA B-fragment order (per dir) ----
// 16384 threads: lm=tid&15, lq=(tid>>4)&3, ct=(tid>>6)&3, kk=(tid>>8)&7, nt=tid>>11
// QKV: nt 0..3 -> Wq cols, 4..5 -> Wk, 6..7 -> Wv.  O: nt 0..3 -> Wo cols.
__global__ __launch_bounds__(256) void w_prep(
    const float* __restrict__ Wq, const float* __restrict__ Wk,
    const float* __restrict__ Wv, const float* __restrict__ Wo,
    unsigned short* __restrict__ Bqkv, unsigned short* __restrict__ Bo)
{
    const int tid = blockIdx.x * 256 + threadIdx.x;
    const int lm = tid & 15, lq = (tid >> 4) & 3, ct = (tid >> 6) & 3;
    const int kk = (tid >> 8) & 7, nt = tid >> 11;
    const int c = ct * 16 + lm;
    {
        const float* W; int ldw, col;
        if (nt < 4)      { W = Wq; ldw = 256; col = nt * 64 + c; }
        else if (nt < 6) { W = Wk; ldw = 128; col = (nt - 4) * 64 + c; }
        else             { W = Wv; ldw = 128; col = (nt - 6) * 64 + c; }
        short8 h8, l8;
        #pragma unroll
        for (int j = 0; j < 8; ++j) {
            int k = kk * 32 + lq * 8 + j;
            unsigned short h, l;
            split2(W[k * ldw + col], h, l);
            h8[j] = (short)h; l8[j] = (short)l;
        }
        int off = boff(nt, kk, ct, lq, lm);
        *(short8*)&Bqkv[off] = h8;
        *(short8*)&Bqkv[off + 8] = l8;
    }
    if (nt < 4) {
        int col = nt * 64 + c;
        short8 h8, l8;
        #pragma unroll
        for (int j = 0; j < 8; ++j) {
            int k = kk * 32 + lq * 8 + j;
            unsigned short h, l;
            split2(Wo[k * 256 + col], h, l);
            h8[j] = (short)h; l8[j] = (short)l;
        }
        int off = boff(nt, kk, ct, lq, lm);
        *(short8*)&Bo[off] = h8;
        *(short8*)&Bo[off + 8] = l8;
    }
}

// ---- fused LN(stats+apply) + QKV projection GEMM (bf16x3) ----
// grid (1024, 2): y=0 -> Q (xq, 256 cols), y=1 -> K|V (xkv, 128+128 cols).
// Waves partition columns (wave w -> cols w*64..w*64+63); A staged once.
__global__ __launch_bounds__(256) void qkv_gemm(
    const float* __restrict__ xq, const float* __restrict__ gq, const float* __restrict__ btq,
    const float* __restrict__ xkv, const float* __restrict__ gkv, const float* __restrict__ btkv,
    const unsigned short* __restrict__ Blin,
    const float* __restrict__ bq, const float* __restrict__ bk, const float* __restrict__ bv,
    unsigned short* __restrict__ Qb, unsigned short* __restrict__ Kb,
    unsigned short* __restrict__ Vb)
{
    __shared__ unsigned short Ah[64 * 256], Al[64 * 256];   // 64 KB
    const int mt = blockIdx.x, y = blockIdx.y, t = threadIdx.x;
    const float* X  = y ? xkv  : xq;
    const float* G  = y ? gkv  : gq;
    const float* BT = y ? btkv : btq;
    const int r0 = mt * 64;
    const int w = t >> 6, l = t & 63;
    // stage A: each wave-iteration covers exactly one full row (64 lanes x float4)
    const float4 gv = *(const float4*)(G + l * 4);
    const float4 b4 = *(const float4*)(BT + l * 4);
    #pragma unroll
    for (int it = 0; it < 16; ++it) {
        int row = it * 4 + w;
        const float4 xv = *(const float4*)(X + xrow_off(r0 + row) + l * 4);
        float s1 = xv.x + xv.y + xv.z + xv.w;
        float s2 = xv.x * xv.x + xv.y * xv.y + xv.z * xv.z + xv.w * xv.w;
        #pragma unroll
        for (int m = 1; m < 64; m <<= 1) {
            s1 += __shfl_xor(s1, m);
            s2 += __shfl_xor(s2, m);
        }
        float mu = s1 * (1.f / 256.f);
        float rstd = rsqrtf(s2 * (1.f / 256.f) - mu * mu + 1e-5f);
        float v0 = (xv.x - mu) * rstd * gv.x + b4.x;
        float v1 = (xv.y - mu) * rstd * gv.y + b4.y;
        float v2 = (xv.z - mu) * rstd * gv.z + b4.z;
        float v3 = (xv.w - mu) * rstd * gv.w + b4.w;
        ushort4 oh, ol;
        split2(v0, oh.x, ol.x); split2(v1, oh.y, ol.y);
        split2(v2, oh.z, ol.z); split2(v3, oh.w, ol.w);
        *(ushort4*)&Ah[sw256(row, l * 4)] = oh;
        *(ushort4*)&Al[sw256(row, l * 4)] = ol;
    }
    __syncthreads();
    const int lm = l & 15, lq = l >> 4;
    const int ntw = y * 4 + w;
    f32x4 acc[4][4] = {};
    #pragma unroll
    for (int kk = 0; kk < 8; ++kk) {
        int k0 = kk * 32 + lq * 8;
        short8 ah[4], al[4];
        #pragma unroll
        for (int m = 0; m < 4; ++m) {
            ah[m] = *(const short8*)&Ah[sw256(m * 16 + lm, k0)];
            al[m] = *(const short8*)&Al[sw256(m * 16 + lm, k0)];
        }
        #pragma unroll
        for (int i = 0; i < 4; ++i) {
            int off = boff(ntw, kk, i, lq, lm);
            short8 bh = *(const short8*)&Blin[off];
            short8 bl = *(const short8*)&Blin[off + 8];
            #pragma unroll
            for (int m = 0; m < 4; ++m) {
                acc[m][i] = __builtin_amdgcn_mfma_f32_16x16x32_bf16(ah[m], bh, acc[m][i], 0, 0, 0);
                acc[m][i] = __builtin_amdgcn_mfma_f32_16x16x32_bf16(al[m], bh, acc[m][i], 0, 0, 0);
                acc[m][i] = __builtin_amdgcn_mfma_f32_16x16x32_bf16(ah[m], bl, acc[m][i], 0, 0, 0);
            }
        }
    }
    #pragma unroll
    for (int i = 0; i < 4; ++i) {
        int cblk = w * 64 + i * 16 + lm;     // col within this block's 256-col slab
        float bias; unsigned short* outp; int ldo, ocol;
        if (y == 0)          { bias = bq[cblk];       outp = Qb; ldo = 256; ocol = cblk; }
        else if (cblk < 128) { bias = bk[cblk];       outp = Kb; ldo = 128; ocol = cblk; }
        else                 { bias = bv[cblk - 128]; outp = Vb; ldo = 128; ocol = cblk - 128; }
        #pragma unroll
        for (int m = 0; m < 4; ++m) {
            #pragma unroll
            for (int rg = 0; rg < 4; ++rg) {
                int row = m * 16 + lq * 4 + rg;
                outp[(r0 + row) * ldo + ocol] = f2b(acc[m][i][rg] + bias);
            }
        }
    }
}

// ---------------- MFMA attention: one block per sequence ----------------
__global__ __launch_bounds__(256) void attn_kernel(
    const unsigned short* __restrict__ Qb, const unsigned short* __restrict__ Kb,
    const unsigned short* __restrict__ Vb, float* __restrict__ Ob)
{
    __shared__ unsigned short VT[128 * 72];      // V^T: [dim][key], stride 72
    __shared__ unsigned short Pl[4 * 64 * 72];   // per-wave P, stride 72
    const int n = blockIdx.x, t = threadIdx.x;
    const int r0 = n * 64;
    #pragma unroll
    for (int it = 0; it < 8; ++it) {
        int idx = it * 256 + t;
        int row = idx >> 5, seg = idx & 31;
        ushort4 v4 = *(const ushort4*)&Vb[(r0 + row) * 128 + seg * 4];
        VT[(seg * 4 + 0) * 72 + row] = v4.x;
        VT[(seg * 4 + 1) * 72 + row] = v4.y;
        VT[(seg * 4 + 2) * 72 + row] = v4.z;
        VT[(seg * 4 + 3) * 72 + row] = v4.w;
    }
    __syncthreads();
    const int wave = t >> 6, l = t & 63, lm = l & 15, lq = l >> 4;
    const int g = wave;
    unsigned short* Pw = &Pl[wave * 64 * 72];
    const float scale = 0.17677669529663687f;    // 1/sqrt(32)
    short8 kf[4];
    #pragma unroll
    for (int nt = 0; nt < 4; ++nt)
        kf[nt] = *(const short8*)&Kb[(r0 + nt * 16 + lm) * 128 + g * 32 + lq * 8];
    #pragma unroll 1
    for (int hi = 0; hi < 2; ++hi) {
        const int h = g * 2 + hi;
        f32x4 s[4][4];
        #pragma unroll
        for (int mt = 0; mt < 4; ++mt) {
            short8 qf = *(const short8*)&Qb[(r0 + mt * 16 + lm) * 256 + h * 32 + lq * 8];
            #pragma unroll
            for (int nt = 0; nt < 4; ++nt) {
                f32x4 z = {0, 0, 0, 0};
                s[mt][nt] = __builtin_amdgcn_mfma_f32_16x16x32_bf16(qf, kf[nt], z, 0, 0, 0);
            }
        }
        #pragma unroll
        for (int mt = 0; mt < 4; ++mt) {
            #pragma unroll
            for (int rg = 0; rg < 4; ++rg) {
                float mx = fmaxf(fmaxf(s[mt][0][rg], s[mt][1][rg]),
                                 fmaxf(s[mt][2][rg], s[mt][3][rg]));
                #pragma unroll
                for (int msk = 1; msk < 16; msk <<= 1)
                    mx = fmaxf(mx, __shfl_xor(mx, msk));
                float p0 = __expf((s[mt][0][rg] - mx) * scale);
                float p1 = __expf((s[mt][1][rg] - mx) * scale);
                float p2 = __expf((s[mt][2][rg] - mx) * scale);
                float p3 = __expf((s[mt][3][rg] - mx) * scale);
                float sum = p0 + p1 + p2 + p3;
                #pragma unroll
                for (int msk = 1; msk < 16; msk <<= 1)
                    sum += __shfl_xor(sum, msk);
                float inv = 1.f / sum;
                int rowb = (mt * 16 + lq * 4 + rg) * 72 + lm;
                Pw[rowb + 0]  = f2b(p0 * inv);
                Pw[rowb + 16] = f2b(p1 * inv);
                Pw[rowb + 32] = f2b(p2 * inv);
                Pw[rowb + 48] = f2b(p3 * inv);
            }
        }
        __syncthreads();
        f32x4 o[4][2] = {{{0,0,0,0},{0,0,0,0}}, {{0,0,0,0},{0,0,0,0}},
                         {{0,0,0,0},{0,0,0,0}}, {{0,0,0,0},{0,0,0,0}}};
        #pragma unroll
        for (int kt = 0; kt < 2; ++kt) {
            short8 vb0 = *(const short8*)&VT[(g * 32 + 0  + lm) * 72 + kt * 32 + lq * 8];
            short8 vb1 = *(const short8*)&VT[(g * 32 + 16 + lm) * 72 + kt * 32 + lq * 8];
            #pragma unroll
            for (int mt = 0; mt < 4; ++mt) {
                short8 pa = *(const short8*)&Pw[(mt * 16 + lm) * 72 + kt * 32 + lq * 8];
                o[mt][0] = __builtin_amdgcn_mfma_f32_16x16x32_bf16(pa, vb0, o[mt][0], 0, 0, 0);
                o[mt][1] = __builtin_amdgcn_mfma_f32_16x16x32_bf16(pa, vb1, o[mt][1], 0, 0, 0);
            }
        }
        __syncthreads();
        #pragma unroll
        for (int mt = 0; mt < 4; ++mt) {
            #pragma unroll
            for (int nt2 = 0; nt2 < 2; ++nt2) {
                #pragma unroll
                for (int rg = 0; rg < 4; ++rg) {
                    int row = mt * 16 + lq * 4 + rg;
                    int col = h * 32 + nt2 * 16 + lm;
                    Ob[(r0 + row) * 256 + col] = o[mt][nt2][rg];
                }
            }
        }
    }
}

// ------- O-projection GEMM (bf16x3) + gate + residual + transpose -------
// grid (1024): waves partition columns; A (fp32 attn out) staged once.
__global__ __launch_bounds__(256) void oproj_gemm(
    const float* __restrict__ Ain, const unsigned short* __restrict__ Bo,
    const float* __restrict__ bo, const float* __restrict__ Xres,
    const float* __restrict__ gate, float* __restrict__ Out)
{
    __shared__ unsigned short Ah[64 * 256], Al[64 * 256];   // 64 KB
    const int mt = blockIdx.x, t = threadIdx.x;
    const int r0 = mt * 64;
    const int w = t >> 6, l = t & 63;
    #pragma unroll
    for (int it = 0; it < 16; ++it) {
        int row = it * 4 + w;
        const float4 a4 = *(const float4*)(Ain + (r0 + row) * 256 + l * 4);
        ushort4 oh, ol;
        split2(a4.x, oh.x, ol.x); split2(a4.y, oh.y, ol.y);
        split2(a4.z, oh.z, ol.z); split2(a4.w, oh.w, ol.w);
        *(ushort4*)&Ah[sw256(row, l * 4)] = oh;
        *(ushort4*)&Al[sw256(row, l * 4)] = ol;
    }
    __syncthreads();
    const int lm = l & 15, lq = l >> 4;
    f32x4 acc[4][4] = {};
    #pragma unroll
    for (int kk = 0; kk < 8; ++kk) {
        int k0 = kk * 32 + lq * 8;
        short8 ah[4], al[4];
        #pragma unroll
        for (int m = 0; m < 4; ++m) {
            ah[m] = *(const short8*)&Ah[sw256(m * 16 + lm, k0)];
            al[m] = *(const short8*)&Al[sw256(m * 16 + lm, k0)];
        }
        #pragma unroll
        for (int i = 0; i < 4; ++i) {
            int off = boff(w, kk, i, lq, lm);
            short8 bh = *(const short8*)&Bo[off];
            short8 bl = *(const short8*)&Bo[off + 8];
            #pragma unroll
            for (int m = 0; m < 4; ++m) {
                acc[m][i] = __builtin_amdgcn_mfma_f32_16x16x32_bf16(ah[m], bh, acc[m][i], 0, 0, 0);
                acc[m][i] = __builtin_amdgcn_mfma_f32_16x16x32_bf16(al[m], bh, acc[m][i], 0, 0, 0);
                acc[m][i] = __builtin_amdgcn_mfma_f32_16x16x32_bf16(ah[m], bl, acc[m][i], 0, 0, 0);
            }
        }
    }
    float sig = 1.f / (1.f + __expf(-gate[0]));
    #pragma unroll
    for (int i = 0; i < 4; ++i) {
        int col = w * 64 + i * 16 + lm;
        float bias = bo[col];
        #pragma unroll
        for (int m = 0; m < 4; ++m) {
            #pragma unroll
            for (int rg = 0; rg < 4; ++rg) {
                int row = m * 16 + lq * 4 + rg;
                int oidx = xrow_off(r0 + row) + col;
                Out[oidx] = Xres[oidx] + sig * (acc[m][i][rg] + bias);
            }
        }
    }
}

extern "C" void kernel_launch(void* const* d_in, const int* in_sizes, int n_in,
                              void* d_out, int out_size, void* d_ws, size_t ws_size,
                              hipStream_t stream) {
    const float* x_spec = (const float*)d_in[0];
    const float* x_spat = (const float*)d_in[1];
    const float* ln_g[4] = {(const float*)d_in[2], (const float*)d_in[4],
                            (const float*)d_in[6], (const float*)d_in[8]};
    const float* ln_b[4] = {(const float*)d_in[3], (const float*)d_in[5],
                            (const float*)d_in[7], (const float*)d_in[9]};
    char* ws = (char*)d_ws;
    // workspace layout (~129.5 MiB)
    unsigned short* Bqkv[2] = {(unsigned short*)ws,
                               (unsigned short*)(ws + (512 << 10))};     // 2 x 512 KiB
    unsigned short* BoL[2]  = {(unsigned short*)(ws + (1024 << 10)),
                               (unsigned short*)(ws + (1280 << 10))};    // 2 x 256 KiB
    char* big = ws + (1536 << 10);
    unsigned short* Qb = (unsigned short*)big;                  // 32 MiB bf16
    unsigned short* Kb = Qb + (size_t)ROWS * 256;               // 16 MiB bf16
    unsigned short* Vb = Kb + (size_t)ROWS * 128;               // 16 MiB bf16
    float* Ab = (float*)(Vb + (size_t)ROWS * 128);              // 64 MiB fp32

    for (int dir = 0; dir < 2; ++dir) {
        int base = 10 + dir * 8;
        w_prep<<<64, 256, 0, stream>>>(
            (const float*)d_in[base + 0], (const float*)d_in[base + 2],
            (const float*)d_in[base + 4], (const float*)d_in[base + 6],
            Bqkv[dir], BoL[dir]);
    }
    for (int dir = 0; dir < 2; ++dir) {
        int base = 10 + dir * 8;
        const float* bq = (const float*)d_in[base + 1];
        const float* bk = (const float*)d_in[base + 3];
        const float* bv = (const float*)d_in[base + 5];
        const float* bo = (const float*)d_in[base + 7];
        const float* gate = (const float*)d_in[26 + dir];
        const float* xq   = dir == 0 ? x_spec : x_spat;
        const float* xkv  = dir == 0 ? x_spat : x_spec;
        const float* gq   = dir == 0 ? ln_g[0] : ln_g[2];
        const float* btq  = dir == 0 ? ln_b[0] : ln_b[2];
        const float* gkv  = dir == 0 ? ln_g[3] : ln_g[1];
        const float* btkv = dir == 0 ? ln_b[3] : ln_b[1];
        float* outp = (float*)d_out + (size_t)dir * NELT;

        qkv_gemm<<<dim3(1024, 2), 256, 0, stream>>>(
            xq, gq, btq, xkv, gkv, btkv, Bqkv[dir],
            bq, bk, bv, Qb, Kb, Vb);
        attn_kernel<<<1024, 256, 0, stream>>>(Qb, Kb, Vb, Ab);
        oproj_gemm<<<1024, 256, 0, stream>>>(Ab, BoL[dir], bo, xq, gate, outp);
    }
}

// Round 2
// 534.376 us; speedup vs baseline: 1.1593x; 1.1593x over previous
//
#include <hip/hip_runtime.h>

typedef short short8 __attribute__((ext_vector_type(8)));
typedef float f32x4 __attribute__((ext_vector_type(4)));

#define NELT 16777216  // B*S*C*D per tensor

__device__ __forceinline__ float b2f(unsigned short u) {
    return __uint_as_float(((unsigned)u) << 16);
}
__device__ __forceinline__ unsigned short f2b(float f) {
    unsigned u = __float_as_uint(f);
    u += 0x7FFF + ((u >> 16) & 1);   // RTN-even
    return (unsigned short)(u >> 16);
}
// Markidis split: f ~= b2f(hi) + b2f(lo)
__device__ __forceinline__ void split2(float f, unsigned short& hi, unsigned short& lo) {
    unsigned short h = f2b(f);
    hi = h;
    lo = f2b(f - b2f(h));
}
// row r of the (BC*S, D) flattened view -> flat offset into x (B,S,C,D)
__device__ __forceinline__ int xrow_off(int r) {
    int n = r >> 6, s = r & 63;
    int b = n >> 7, c = n & 127;
    return (((b << 6) + s) * 128 + c) << 8;
}
// XOR-swizzled LDS element offset, 64x256 bf16 tile, 8-elem chunks.
__device__ __forceinline__ int sw256(int row, int k) {
    return row * 256 + ((((k >> 3) ^ (row & 7)) << 3) | (k & 7));
}
// linearized B-fragment offset (in shorts): [nt][kk][ct][lq][lm][hi8|lo8]
__device__ __forceinline__ int boff(int nt, int kk, int ct, int lq, int lm) {
    return ((((nt * 8 + kk) * 4 + ct) * 4 + lq) * 16 + lm) * 16;
}

// ---- weight pre-linearization into MFMA B-fragment order (per dir) ----
__global__ __launch_bounds__(256) void w_prep(
    const float* __restrict__ Wq, const float* __restrict__ Wk,
    const float* __restrict__ Wv, const float* __restrict__ Wo,
    unsigned short* __restrict__ Bqkv, unsigned short* __restrict__ Bo)
{
    const int tid = blockIdx.x * 256 + threadIdx.x;
    const int lm = tid & 15, lq = (tid >> 4) & 3, ct = (tid >> 6) & 3;
    const int kk = (tid >> 8) & 7, nt = tid >> 11;
    const int c = ct * 16 + lm;
    {
        const float* W; int ldw, col;
        if (nt < 4)      { W = Wq; ldw = 256; col = nt * 64 + c; }
        else if (nt < 6) { W = Wk; ldw = 128; col = (nt - 4) * 64 + c; }
        else             { W = Wv; ldw = 128; col = (nt - 6) * 64 + c; }
        short8 h8, l8;
        #pragma unroll
        for (int j = 0; j < 8; ++j) {
            int k = kk * 32 + lq * 8 + j;
            unsigned short h, l;
            split2(W[k * ldw + col], h, l);
            h8[j] = (short)h; l8[j] = (short)l;
        }
        int off = boff(nt, kk, ct, lq, lm);
        *(short8*)&Bqkv[off] = h8;
        *(short8*)&Bqkv[off + 8] = l8;
    }
    if (nt < 4) {
        int col = nt * 64 + c;
        short8 h8, l8;
        #pragma unroll
        for (int j = 0; j < 8; ++j) {
            int k = kk * 32 + lq * 8 + j;
            unsigned short h, l;
            split2(Wo[k * 256 + col], h, l);
            h8[j] = (short)h; l8[j] = (short)l;
        }
        int off = boff(nt, kk, ct, lq, lm);
        *(short8*)&Bo[off] = h8;
        *(short8*)&Bo[off + 8] = l8;
    }
}

struct FusedArgs {
    const float* xq[2];   const float* xkv[2];
    const float* gq[2];   const float* btq[2];
    const float* gkv[2];  const float* btkv[2];
    const unsigned short* Bqkv[2];
    const unsigned short* Bow[2];
    const float* bq[2];   const float* bk[2];
    const float* bv[2];   const float* bo[2];
    const float* gate[2];
    float* out[2];
};

// ======================= fully-fused per-sequence kernel ==================
// grid (1024, 2): x = sequence (b*128+c), y = direction.
// One block does: LN(xkv)->K,V ; LN(xq)->Q ; attention ; O-proj+residual.
// LDS: one 64 KiB region, time-multiplexed:
//   [stage xkv Ah/Al] -> [per-wave K/V repack slots] -> [stage xq Ah/Al]
//   -> [per-wave Q repack + P slots] -> [attn-out Ah/Al].
__global__ __launch_bounds__(256, 2) void fused(FusedArgs P_)
{
    __shared__ char SM[65536];
    unsigned short* Ah = (unsigned short*)SM;              // [64*256]
    unsigned short* Al = (unsigned short*)(SM + 32768);
    const int dir = blockIdx.y;
    const int n = blockIdx.x, t = threadIdx.x;
    const int r0 = n * 64;
    const int w = t >> 6, l = t & 63, lm = l & 15, lq = l >> 4;
    unsigned short* slot = (unsigned short*)(SM + w * 16384);  // per-wave 16 KiB

    const float* xq  = P_.xq[dir];
    const float* xkv = P_.xkv[dir];
    const unsigned short* Bq  = P_.Bqkv[dir];
    const unsigned short* BoW = P_.Bow[dir];

    // ---------------- staging helper: LN + split2 into Ah/Al --------------
    auto stage = [&](const float* X, const float* G, const float* BT) {
        float4 xv[16];
        #pragma unroll
        for (int it = 0; it < 16; ++it)
            xv[it] = *(const float4*)(X + xrow_off(r0 + it * 4 + w) + l * 4);
        const float4 gv = *(const float4*)(G + l * 4);
        const float4 b4 = *(const float4*)(BT + l * 4);
        #pragma unroll
        for (int it = 0; it < 16; ++it) {
            int row = it * 4 + w;
            float4 x4 = xv[it];
            float s1 = x4.x + x4.y + x4.z + x4.w;
            float s2 = x4.x * x4.x + x4.y * x4.y + x4.z * x4.z + x4.w * x4.w;
            #pragma unroll
            for (int m = 1; m < 64; m <<= 1) {
                s1 += __shfl_xor(s1, m);
                s2 += __shfl_xor(s2, m);
            }
            float mu = s1 * (1.f / 256.f);
            float rstd = rsqrtf(s2 * (1.f / 256.f) - mu * mu + 1e-5f);
            float v0 = (x4.x - mu) * rstd * gv.x + b4.x;
            float v1 = (x4.y - mu) * rstd * gv.y + b4.y;
            float v2 = (x4.z - mu) * rstd * gv.z + b4.z;
            float v3 = (x4.w - mu) * rstd * gv.w + b4.w;
            ushort4 oh, ol;
            split2(v0, oh.x, ol.x); split2(v1, oh.y, ol.y);
            split2(v2, oh.z, ol.z); split2(v3, oh.w, ol.w);
            *(ushort4*)&Ah[sw256(row, l * 4)] = oh;
            *(ushort4*)&Al[sw256(row, l * 4)] = ol;
        }
    };

    // ============ phase 1: stage LN(xkv); phase 2: K,V projection =========
    stage(xkv, P_.gkv[dir], P_.btkv[dir]);
    __syncthreads();

    f32x4 kacc[4][2] = {};
    f32x4 vacc[4][2] = {};
    {
        const int ntK = 4 + (w >> 1), ntV = 6 + (w >> 1);
        #pragma unroll
        for (int kk = 0; kk < 8; ++kk) {
            int k0 = kk * 32 + lq * 8;
            short8 ah[4], al[4];
            #pragma unroll
            for (int m = 0; m < 4; ++m) {
                ah[m] = *(const short8*)&Ah[sw256(m * 16 + lm, k0)];
                al[m] = *(const short8*)&Al[sw256(m * 16 + lm, k0)];
            }
            #pragma unroll
            for (int i = 0; i < 2; ++i) {
                int ct = (2 * w + i) & 3;
                int offK = boff(ntK, kk, ct, lq, lm);
                short8 bh = *(const short8*)&Bq[offK];
                short8 bl = *(const short8*)&Bq[offK + 8];
                #pragma unroll
                for (int m = 0; m < 4; ++m) {
                    kacc[m][i] = __builtin_amdgcn_mfma_f32_16x16x32_bf16(ah[m], bh, kacc[m][i], 0, 0, 0);
                    kacc[m][i] = __builtin_amdgcn_mfma_f32_16x16x32_bf16(al[m], bh, kacc[m][i], 0, 0, 0);
                    kacc[m][i] = __builtin_amdgcn_mfma_f32_16x16x32_bf16(ah[m], bl, kacc[m][i], 0, 0, 0);
                }
                int offV = boff(ntV, kk, ct, lq, lm);
                bh = *(const short8*)&Bq[offV];
                bl = *(const short8*)&Bq[offV + 8];
                #pragma unroll
                for (int m = 0; m < 4; ++m) {
                    vacc[m][i] = __builtin_amdgcn_mfma_f32_16x16x32_bf16(ah[m], bh, vacc[m][i], 0, 0, 0);
                    vacc[m][i] = __builtin_amdgcn_mfma_f32_16x16x32_bf16(al[m], bh, vacc[m][i], 0, 0, 0);
                    vacc[m][i] = __builtin_amdgcn_mfma_f32_16x16x32_bf16(ah[m], bl, vacc[m][i], 0, 0, 0);
                }
            }
        }
    }
    __syncthreads();   // all waves done reading Ah/Al(xkv); slots may be written

    // ====== phase 3: K/V repack (wave-local) C-layout -> frag layout ======
    // Kslot [64 keys][stride 40]; Vslot = V^T [32 dims][stride 72]
    unsigned short* Ks = slot;
    unsigned short* Vs = slot + 2560;
    {
        float bkv0 = P_.bk[dir][w * 32 + lm],  bkv1 = P_.bk[dir][w * 32 + 16 + lm];
        float bvv0 = P_.bv[dir][w * 32 + lm],  bvv1 = P_.bv[dir][w * 32 + 16 + lm];
        #pragma unroll
        for (int m = 0; m < 4; ++m) {
            #pragma unroll
            for (int rg = 0; rg < 4; ++rg) {
                int key = m * 16 + lq * 4 + rg;
                Ks[key * 40 + lm]      = f2b(kacc[m][0][rg] + bkv0);
                Ks[key * 40 + 16 + lm] = f2b(kacc[m][1][rg] + bkv1);
                Vs[lm * 72 + key]        = f2b(vacc[m][0][rg] + bvv0);
                Vs[(16 + lm) * 72 + key] = f2b(vacc[m][1][rg] + bvv1);
            }
        }
    }
    short8 kf[4];
    #pragma unroll
    for (int nt = 0; nt < 4; ++nt)
        kf[nt] = *(const short8*)&Ks[(nt * 16 + lm) * 40 + lq * 8];
    short8 vb[2][2];
    #pragma unroll
    for (int kt = 0; kt < 2; ++kt) {
        vb[kt][0] = *(const short8*)&Vs[lm * 72 + kt * 32 + lq * 8];
        vb[kt][1] = *(const short8*)&Vs[(16 + lm) * 72 + kt * 32 + lq * 8];
    }
    __syncthreads();   // frags in regs; LDS free for xq staging

    // ============ phase 4: stage LN(xq); phase 5: Q projection ============
    stage(xq, P_.gq[dir], P_.btq[dir]);
    __syncthreads();

    f32x4 qacc[4][4] = {};
    #pragma unroll
    for (int kk = 0; kk < 8; ++kk) {
        int k0 = kk * 32 + lq * 8;
        short8 ah[4], al[4];
        #pragma unroll
        for (int m = 0; m < 4; ++m) {
            ah[m] = *(const short8*)&Ah[sw256(m * 16 + lm, k0)];
            al[m] = *(const short8*)&Al[sw256(m * 16 + lm, k0)];
        }
        #pragma unroll
        for (int i = 0; i < 4; ++i) {
            int off = boff(w, kk, i, lq, lm);
            short8 bh = *(const short8*)&Bq[off];
            short8 bl = *(const short8*)&Bq[off + 8];
            #pragma unroll
            for (int m = 0; m < 4; ++m) {
                qacc[m][i] = __builtin_amdgcn_mfma_f32_16x16x32_bf16(ah[m], bh, qacc[m][i], 0, 0, 0);
                qacc[m][i] = __builtin_amdgcn_mfma_f32_16x16x32_bf16(al[m], bh, qacc[m][i], 0, 0, 0);
                qacc[m][i] = __builtin_amdgcn_mfma_f32_16x16x32_bf16(ah[m], bl, qacc[m][i], 0, 0, 0);
            }
        }
    }
    __syncthreads();   // all waves done reading Ah/Al(xq); slots may be written

    // ====== phase 6: Q repack (wave-local), then attention ======
    // Qslot [64 rows][stride 72]; P reuses the same bytes after qf reads.
    unsigned short* Qs = slot;
    {
        float bq0 = P_.bq[dir][w * 64 + lm],      bq1 = P_.bq[dir][w * 64 + 16 + lm];
        float bq2 = P_.bq[dir][w * 64 + 32 + lm], bq3 = P_.bq[dir][w * 64 + 48 + lm];
        #pragma unroll
        for (int m = 0; m < 4; ++m) {
            #pragma unroll
            for (int rg = 0; rg < 4; ++rg) {
                int row = (m * 16 + lq * 4 + rg) * 72;
                Qs[row + lm]      = f2b(qacc[m][0][rg] + bq0);
                Qs[row + 16 + lm] = f2b(qacc[m][1][rg] + bq1);
                Qs[row + 32 + lm] = f2b(qacc[m][2][rg] + bq2);
                Qs[row + 48 + lm] = f2b(qacc[m][3][rg] + bq3);
            }
        }
    }
    short8 qf[2][4];
    #pragma unroll
    for (int hi = 0; hi < 2; ++hi)
        #pragma unroll
        for (int mt = 0; mt < 4; ++mt)
            qf[hi][mt] = *(const short8*)&Qs[(mt * 16 + lm) * 72 + hi * 32 + lq * 8];

    unsigned short* Pw = slot;   // overwrites Q bytes (qf already in regs)
    const float scale = 0.17677669529663687f;    // 1/sqrt(32)
    f32x4 o[2][4][2] = {};
    #pragma unroll
    for (int hi = 0; hi < 2; ++hi) {
        f32x4 s[4][4];
        #pragma unroll
        for (int mt = 0; mt < 4; ++mt) {
            #pragma unroll
            for (int nt = 0; nt < 4; ++nt) {
                f32x4 z = {0, 0, 0, 0};
                s[mt][nt] = __builtin_amdgcn_mfma_f32_16x16x32_bf16(qf[hi][mt], kf[nt], z, 0, 0, 0);
            }
        }
        #pragma unroll
        for (int mt = 0; mt < 4; ++mt) {
            #pragma unroll
            for (int rg = 0; rg < 4; ++rg) {
                float mx = fmaxf(fmaxf(s[mt][0][rg], s[mt][1][rg]),
                                 fmaxf(s[mt][2][rg], s[mt][3][rg]));
                #pragma unroll
                for (int msk = 1; msk < 16; msk <<= 1)
                    mx = fmaxf(mx, __shfl_xor(mx, msk));
                float p0 = __expf((s[mt][0][rg] - mx) * scale);
                float p1 = __expf((s[mt][1][rg] - mx) * scale);
                float p2 = __expf((s[mt][2][rg] - mx) * scale);
                float p3 = __expf((s[mt][3][rg] - mx) * scale);
                float sum = p0 + p1 + p2 + p3;
                #pragma unroll
                for (int msk = 1; msk < 16; msk <<= 1)
                    sum += __shfl_xor(sum, msk);
                float inv = 1.f / sum;
                int rowb = (mt * 16 + lq * 4 + rg) * 72 + lm;
                Pw[rowb + 0]  = f2b(p0 * inv);
                Pw[rowb + 16] = f2b(p1 * inv);
                Pw[rowb + 32] = f2b(p2 * inv);
                Pw[rowb + 48] = f2b(p3 * inv);
            }
        }
        #pragma unroll
        for (int kt = 0; kt < 2; ++kt) {
            #pragma unroll
            for (int mt = 0; mt < 4; ++mt) {
                short8 pa = *(const short8*)&Pw[(mt * 16 + lm) * 72 + kt * 32 + lq * 8];
                o[hi][mt][0] = __builtin_amdgcn_mfma_f32_16x16x32_bf16(pa, vb[kt][0], o[hi][mt][0], 0, 0, 0);
                o[hi][mt][1] = __builtin_amdgcn_mfma_f32_16x16x32_bf16(pa, vb[kt][1], o[hi][mt][1], 0, 0, 0);
            }
        }
    }
    __syncthreads();   // all waves done with P slots; LDS free for attn-out

    // ====== phase 7: attn-out -> Ah/Al (split bf16, swizzled) ======
    #pragma unroll
    for (int hi = 0; hi < 2; ++hi) {
        #pragma unroll
        for (int mt = 0; mt < 4; ++mt) {
            #pragma unroll
            for (int n2 = 0; n2 < 2; ++n2) {
                #pragma unroll
                for (int rg = 0; rg < 4; ++rg) {
                    int row = mt * 16 + lq * 4 + rg;
                    int col = w * 64 + hi * 32 + n2 * 16 + lm;
                    unsigned short h_, l_;
                    split2(o[hi][mt][n2][rg], h_, l_);
                    int sw = sw256(row, col);
                    Ah[sw] = h_;
                    Al[sw] = l_;
                }
            }
        }
    }
    __syncthreads();

    // ====== phase 8: O-projection + gate + residual + transpose ======
    f32x4 acc[4][4] = {};
    #pragma unroll
    for (int kk = 0; kk < 8; ++kk) {
        int k0 = kk * 32 + lq * 8;
        short8 ah[4], al[4];
        #pragma unroll
        for (int m = 0; m < 4; ++m) {
            ah[m] = *(const short8*)&Ah[sw256(m * 16 + lm, k0)];
            al[m] = *(const short8*)&Al[sw256(m * 16 + lm, k0)];
        }
        #pragma unroll
        for (int i = 0; i < 4; ++i) {
            int off = boff(w, kk, i, lq, lm);
            short8 bh = *(const short8*)&BoW[off];
            short8 bl = *(const short8*)&BoW[off + 8];
            #pragma unroll
            for (int m = 0; m < 4; ++m) {
                acc[m][i] = __builtin_amdgcn_mfma_f32_16x16x32_bf16(ah[m], bh, acc[m][i], 0, 0, 0);
                acc[m][i] = __builtin_amdgcn_mfma_f32_16x16x32_bf16(al[m], bh, acc[m][i], 0, 0, 0);
                acc[m][i] = __builtin_amdgcn_mfma_f32_16x16x32_bf16(ah[m], bl, acc[m][i], 0, 0, 0);
            }
        }
    }
    float sig = 1.f / (1.f + __expf(-P_.gate[dir][0]));
    const float* Xres = xq;
    float* Out = P_.out[dir];
    #pragma unroll
    for (int i = 0; i < 4; ++i) {
        int col = w * 64 + i * 16 + lm;
        float bias = P_.bo[dir][col];
        #pragma unroll
        for (int m = 0; m < 4; ++m) {
            #pragma unroll
            for (int rg = 0; rg < 4; ++rg) {
                int row = m * 16 + lq * 4 + rg;
                int oidx = xrow_off(r0 + row) + col;
                Out[oidx] = Xres[oidx] + sig * (acc[m][i][rg] + bias);
            }
        }
    }
}

extern "C" void kernel_launch(void* const* d_in, const int* in_sizes, int n_in,
                              void* d_out, int out_size, void* d_ws, size_t ws_size,
                              hipStream_t stream) {
    const float* x_spec = (const float*)d_in[0];
    const float* x_spat = (const float*)d_in[1];
    const float* ln_g[4] = {(const float*)d_in[2], (const float*)d_in[4],
                            (const float*)d_in[6], (const float*)d_in[8]};
    const float* ln_b[4] = {(const float*)d_in[3], (const float*)d_in[5],
                            (const float*)d_in[7], (const float*)d_in[9]};
    char* ws = (char*)d_ws;
    unsigned short* Bqkv[2] = {(unsigned short*)ws,
                               (unsigned short*)(ws + (512 << 10))};     // 2 x 512 KiB
    unsigned short* BoL[2]  = {(unsigned short*)(ws + (1024 << 10)),
                               (unsigned short*)(ws + (1280 << 10))};    // 2 x 256 KiB

    for (int dir = 0; dir < 2; ++dir) {
        int base = 10 + dir * 8;
        w_prep<<<64, 256, 0, stream>>>(
            (const float*)d_in[base + 0], (const float*)d_in[base + 2],
            (const float*)d_in[base + 4], (const float*)d_in[base + 6],
            Bqkv[dir], BoL[dir]);
    }

    FusedArgs A;
    for (int dir = 0; dir < 2; ++dir) {
        int base = 10 + dir * 8;
        A.xq[dir]   = dir == 0 ? x_spec : x_spat;
        A.xkv[dir]  = dir == 0 ? x_spat : x_spec;
        A.gq[dir]   = dir == 0 ? ln_g[0] : ln_g[2];
        A.btq[dir]  = dir == 0 ? ln_b[0] : ln_b[2];
        A.gkv[dir]  = dir == 0 ? ln_g[3] : ln_g[1];
        A.btkv[dir] = dir == 0 ? ln_b[3] : ln_b[1];
        A.Bqkv[dir] = Bqkv[dir];
        A.Bow[dir]  = BoL[dir];
        A.bq[dir]   = (const float*)d_in[base + 1];
        A.bk[dir]   = (const float*)d_in[base + 3];
        A.bv[dir]   = (const float*)d_in[base + 5];
        A.bo[dir]   = (const float*)d_in[base + 7];
        A.gate[dir] = (const float*)d_in[26 + dir];
        A.out[dir]  = (float*)d_out + (size_t)dir * NELT;
    }
    fused<<<dim3(1024, 2), 256, 0, stream>>>(A);
}